// Round 11
// baseline (248.922 us; speedup 1.0000x reference)
//
#include <hip/hip_runtime.h>
#include <hip/hip_bf16.h>
#include <math.h>

// Problem constants (match reference)
#define N_NODES 50000
#define N_EDGES 800000
#define DIM 64
#define NEG_SLOPE 0.2f
#define EPS 1e-5f

typedef __attribute__((ext_vector_type(8))) short short8v;  // 8 bf16 (4 VGPRs)
typedef __attribute__((ext_vector_type(4))) float f32x4;    // MFMA accumulator

union frag_u { unsigned u[8]; short8v v[2]; };

__device__ __forceinline__ float lrelu(float v) { return fmaxf(v, NEG_SLOPE * v); }

__device__ __forceinline__ unsigned short bfbits(float v) {
    return __bfloat16_as_ushort(__float2bfloat16(v));
}
// packed pair f32->bf16
__device__ __forceinline__ unsigned pack2bf(float a, float b) {
    union { __hip_bfloat162 h; unsigned u; } cvt;
    cvt.h = __float22bfloat162_rn(make_float2(a, b));
    return cvt.u;
}

// Swizzled byte offset into a 128-byte-stride LDS tile (node_kernel only).
__device__ __forceinline__ unsigned swz(unsigned row, unsigned byteInRow) {
    return row * 128u + (byteInRow ^ ((row & 7u) << 4));
}

#define LDS_BUF 16384  // 128 rows x 128 bytes

// Fragment-layout weight store: matrix m, entry idx=(ks*4+g)*64+col holds
// short8 {bf16(W[k(ks,g,j)][col]), j=0..7}, used as MFMA A-operand (W^T).
// Matrices 0 (w1), 4 (pAw), 5 (pBw): standard k = 32ks+8g+j.
// Matrices 1 (w2), 2 (Bw), 3 (Cw): PERMUTED k = pi(ks,g,j) =
//   16*(2ks + (j>>2)) + 4g + (j&3)
// so the previous phase's C-layout output IS the next phase's B-fragment
// after cvt_pk packing (verified numerically in r9: absmax identical).
#define WFRAG_ENTRIES 512   // 2ks * 4g * 64col per matrix

#define SCANA_BLOCKS 49     // 49*1024 = 50176 >= 50000

// ---------------------------------------------------------------------------
// prep: blocks 0..5 convert weight matrices fp32 -> fragment bf16;
//       blocks 6..54 zero cnt (absorbs the memset dispatch)
// ---------------------------------------------------------------------------
__global__ __launch_bounds__(256) void prep_kernel(
    const float* __restrict__ w1, const float* __restrict__ w2,
    const float* __restrict__ Bw, const float* __restrict__ Cw,
    const float* __restrict__ pAw, const float* __restrict__ pBw,
    unsigned short* __restrict__ wbf, int* __restrict__ cnt)
{
    const int t = threadIdx.x;
    if (blockIdx.x >= 6) {
        const int idx = (blockIdx.x - 6) * 1024 + t * 4;
        if (idx + 3 < N_NODES) {
            int4 z = {0, 0, 0, 0};
            *(int4*)(cnt + idx) = z;
        } else {
#pragma unroll
            for (int i = 0; i < 4; ++i)
                if (idx + i < N_NODES) cnt[idx + i] = 0;
        }
        return;
    }
    const float* W;
    switch (blockIdx.x) {
        case 0: W = w1; break;
        case 1: W = w2; break;
        case 2: W = Bw; break;
        case 3: W = Cw; break;
        case 4: W = pAw; break;
        default: W = pBw; break;
    }
    const bool permuted = (blockIdx.x >= 1 && blockIdx.x <= 3);
#pragma unroll
    for (int ii = 0; ii < 2; ++ii) {
        const int idx = t * 2 + ii;          // 0..511
        const int ks  = idx >> 8;
        const int g   = (idx >> 6) & 3;
        const int col = idx & 63;
        unsigned short* o = wbf + (size_t)blockIdx.x * 4096 + (size_t)idx * 8;
#pragma unroll
        for (int j = 0; j < 8; ++j) {
            const int k = permuted ? (16 * (2 * ks + (j >> 2)) + 4 * g + (j & 3))
                                   : (32 * ks + 8 * g + j);
            o[j] = bfbits(W[k * DIM + col]);
        }
    }
}

// fragment fetch helper (m = matrix id, ks = k-step)
__device__ __forceinline__ short8v wfrag(const unsigned short* wbf, int m, int ks,
                                         int g, int col) {
    return ((const short8v*)wbf)[m * WFRAG_ENTRIES + (ks * 4 + g) * 64 + col];
}

// ---------------------------------------------------------------------------
// Node pooling via MFMA (matrices 4,5 standard layout)
// ---------------------------------------------------------------------------
__global__ __launch_bounds__(256) void node_kernel(
    const float* __restrict__ V,
    const unsigned short* __restrict__ wbf,
    const float* __restrict__ pAb, const float* __restrict__ pBb,
    float* __restrict__ Vp)
{
    __shared__ __align__(16) unsigned char sm[2 * LDS_BUF];
    unsigned char* bufA = sm;
    unsigned char* bufB = sm + LDS_BUF;

    const int t    = threadIdx.x;
    const int w    = t >> 6;
    const int lane = t & 63;
    const int g    = lane >> 4;
    const int c    = lane & 15;
    const int col  = 16 * w + c;
    const unsigned colbyte = (unsigned)col * 2;
    const int base = blockIdx.x * 128;

    {
        const int row = t >> 1;
        const int n = base + row;
        if (n < N_NODES) {
            const float4* Vr = (const float4*)(V + (size_t)n * DIM + (t & 1) * 32);
#pragma unroll
            for (int ci = 0; ci < 4; ++ci) {
                float4 qa = Vr[2 * ci];
                float4 qb = Vr[2 * ci + 1];
                uint4 u;
                u.x = pack2bf(lrelu(qa.x), lrelu(qa.y));
                u.y = pack2bf(lrelu(qa.z), lrelu(qa.w));
                u.z = pack2bf(lrelu(qb.x), lrelu(qb.y));
                u.w = pack2bf(lrelu(qb.z), lrelu(qb.w));
                *(uint4*)(bufA + swz(row, (t & 1) * 64 + 16 * ci)) = u;
            }
        } else {
            uint4 z = {0u, 0u, 0u, 0u};
#pragma unroll
            for (int ci = 0; ci < 4; ++ci)
                *(uint4*)(bufA + swz(row, (t & 1) * 64 + 16 * ci)) = z;
        }
    }

    const short8v af0 = wfrag(wbf, 4, 0, g, col), af1 = wfrag(wbf, 4, 1, g, col);
    const short8v bf0 = wfrag(wbf, 5, 0, g, col), bf1 = wfrag(wbf, 5, 1, g, col);
    const float bbA = pAb[col], bbB = pBb[col];

    __syncthreads();

#pragma unroll
    for (int mt = 0; mt < 8; ++mt) {
        const int arow = mt * 16 + c;
        short8v a0 = *(const short8v*)(bufA + swz(arow, 16 * g));
        short8v a1 = *(const short8v*)(bufA + swz(arow, 64 + 16 * g));
        f32x4 acc = {0.f, 0.f, 0.f, 0.f};
        acc = __builtin_amdgcn_mfma_f32_16x16x32_bf16(a0, af0, acc, 0, 0, 0);
        acc = __builtin_amdgcn_mfma_f32_16x16x32_bf16(a1, af1, acc, 0, 0, 0);
#pragma unroll
        for (int r = 0; r < 4; ++r) {
            const float v = lrelu(acc[r] + bbA);
            *(unsigned short*)(bufB + swz(mt * 16 + 4 * g + r, colbyte)) = bfbits(v);
        }
    }
    __syncthreads();

#pragma unroll
    for (int mt = 0; mt < 8; ++mt) {
        const int arow = mt * 16 + c;
        short8v a0 = *(const short8v*)(bufB + swz(arow, 16 * g));
        short8v a1 = *(const short8v*)(bufB + swz(arow, 64 + 16 * g));
        f32x4 acc = {0.f, 0.f, 0.f, 0.f};
        acc = __builtin_amdgcn_mfma_f32_16x16x32_bf16(a0, bf0, acc, 0, 0, 0);
        acc = __builtin_amdgcn_mfma_f32_16x16x32_bf16(a1, bf1, acc, 0, 0, 0);
#pragma unroll
        for (int r = 0; r < 4; ++r) {
            const int n = base + mt * 16 + 4 * g + r;
            if (n < N_NODES) Vp[(size_t)n * DIM + col] = acc[r] + bbB;
        }
    }
}

// ---------------------------------------------------------------------------
// hist: per-dst count AND per-edge rank (slot within its node)
// ---------------------------------------------------------------------------
__global__ __launch_bounds__(256) void hist_kernel(
    const int* __restrict__ dst, int* __restrict__ cnt, int* __restrict__ rank)
{
    const int e = blockIdx.x * 256 + threadIdx.x;   // 800000 % 256 == 0
    rank[e] = atomicAdd(&cnt[dst[e]], 1);
}

// ---------------------------------------------------------------------------
// two-level scan
// ---------------------------------------------------------------------------
__global__ __launch_bounds__(256) void scanA_kernel(
    const int* __restrict__ cnt, int* __restrict__ lofs, int* __restrict__ btot)
{
    __shared__ int ts[256];
    const int t = threadIdx.x;
    const int nb = blockIdx.x * 1024 + t * 4;
    int4 c = {0, 0, 0, 0};
    if (nb + 3 < N_NODES) {
        c = *(const int4*)(cnt + nb);
    } else {
        if (nb + 0 < N_NODES) c.x = cnt[nb + 0];
        if (nb + 1 < N_NODES) c.y = cnt[nb + 1];
        if (nb + 2 < N_NODES) c.z = cnt[nb + 2];
        if (nb + 3 < N_NODES) c.w = cnt[nb + 3];
    }
    ts[t] = c.x + c.y + c.z + c.w;
    __syncthreads();
    for (int off = 1; off < 256; off <<= 1) {
        const int add = (t >= off) ? ts[t - off] : 0;
        __syncthreads();
        ts[t] += add;
        __syncthreads();
    }
    int4 o;
    o.x = (t == 0) ? 0 : ts[t - 1];
    o.y = o.x + c.x;
    o.z = o.y + c.y;
    o.w = o.z + c.z;
    if (nb + 3 < N_NODES) {
        *(int4*)(lofs + nb) = o;
    } else {
        if (nb + 0 < N_NODES) lofs[nb + 0] = o.x;
        if (nb + 1 < N_NODES) lofs[nb + 1] = o.y;
        if (nb + 2 < N_NODES) lofs[nb + 2] = o.z;
        if (nb + 3 < N_NODES) lofs[nb + 3] = o.w;
    }
    if (t == 255) btot[blockIdx.x] = ts[255];
}

__global__ __launch_bounds__(64) void scanB_kernel(
    const int* __restrict__ btot, int* __restrict__ bbase)
{
    const int t = threadIdx.x;    // one wave
    const int own = (t < SCANA_BLOCKS) ? btot[t] : 0;
    int v = own;
    for (int off = 1; off < 64; off <<= 1) {
        const int u = __shfl_up(v, off, 64);
        if (t >= off) v += u;
    }
    if (t < SCANA_BLOCKS) bbase[t] = v - own;   // exclusive
}

// ---------------------------------------------------------------------------
// ALL-REGISTER transposed-dual MFMA edge pipeline. ZERO LDS, ZERO barriers.
// 256 threads = 4 waves; each wave owns 16 edges (edge = lane&15 of its tile).
// FIX vs r9: __launch_bounds__(256,1) lifts the VGPR cap, and ALL 32 weight
// fragments are hoisted to kernel entry — one burst of independent b128 loads
// (L2 latency paid once, overlapped with E/Vp loads) instead of per-phase
// critical-path reloads at 48 VGPRs.
// ---------------------------------------------------------------------------
__global__ __launch_bounds__(256, 1) void edge_kernel(
    const float* __restrict__ E,
    const int* __restrict__ src, const int* __restrict__ dst,
    const int* __restrict__ rank,
    const int* __restrict__ lofs, const int* __restrict__ bbase,
    const unsigned short* __restrict__ wbf,
    const float* __restrict__ b1, const float* __restrict__ b2,
    const float* __restrict__ Bb, const float* __restrict__ Cb,
    const float* __restrict__ Vp,
    __hip_bfloat16* __restrict__ msg)
{
    const int t    = threadIdx.x;
    const int lane = t & 63;
    const int c    = lane & 15;
    const int hi   = lane >> 4;
    const int e    = blockIdx.x * 64 + (t >> 6) * 16 + c;  // this lane's edge

    // ---- early scattered loads: CSR slot, src, Vp gather ----
    const int d_my = dst[e];
    const int s0   = src[e];
    const int pos  = lofs[d_my] + bbase[d_my >> 10] + rank[e];

    float4 vpre[4];
#pragma unroll
    for (int m = 0; m < 4; ++m)
        vpre[m] = *(const float4*)(Vp + (size_t)s0 * DIM + 16 * m + 4 * hi);

    // ---- hoisted weight fragments: 32 independent b128 loads, one burst ----
    short8v wf[4][2][4];   // [mat][ks][m] — all indices compile-time (unrolled)
#pragma unroll
    for (int mat = 0; mat < 4; ++mat)
#pragma unroll
        for (int ks = 0; ks < 2; ++ks)
#pragma unroll
            for (int m = 0; m < 4; ++m)
                wf[mat][ks][m] = wfrag(wbf, mat, ks, hi, 16 * m + c);

    // ---- E row -> B-fragments (standard k order: k = 32ks + 8hi + j) ----
    short8v xb0, xb1;
    {
        const float* Ep = E + (size_t)e * DIM + 8 * hi;
        const float4 qa = *(const float4*)(Ep + 0);
        const float4 qb = *(const float4*)(Ep + 4);
        const float4 qc = *(const float4*)(Ep + 32);
        const float4 qd = *(const float4*)(Ep + 36);
        frag_u f;
        f.u[0] = pack2bf(qa.x, qa.y); f.u[1] = pack2bf(qa.z, qa.w);
        f.u[2] = pack2bf(qb.x, qb.y); f.u[3] = pack2bf(qb.z, qb.w);
        f.u[4] = pack2bf(qc.x, qc.y); f.u[5] = pack2bf(qc.z, qc.w);
        f.u[6] = pack2bf(qd.x, qd.y); f.u[7] = pack2bf(qd.z, qd.w);
        xb0 = f.v[0]; xb1 = f.v[1];
    }

    // One relu phase: xb <- relu(W^T x + b). Output C-layout packs directly
    // into the next B-fragments (pi baked into the NEXT phase's weights).
#define PHASE(MAT, BIASP)                                                         \
    {                                                                             \
        frag_u nx;                                                                \
        _Pragma("unroll")                                                         \
        for (int m = 0; m < 4; ++m) {                                             \
            f32x4 acc = {0.f, 0.f, 0.f, 0.f};                                     \
            acc = __builtin_amdgcn_mfma_f32_16x16x32_bf16(wf[MAT][0][m], xb0, acc, 0, 0, 0); \
            acc = __builtin_amdgcn_mfma_f32_16x16x32_bf16(wf[MAT][1][m], xb1, acc, 0, 0, 0); \
            const float4 bias = *(const float4*)(BIASP + 16 * m + 4 * hi);        \
            nx.u[2 * m]     = pack2bf(fmaxf(acc[0] + bias.x, 0.f),                \
                                      fmaxf(acc[1] + bias.y, 0.f));               \
            nx.u[2 * m + 1] = pack2bf(fmaxf(acc[2] + bias.z, 0.f),                \
                                      fmaxf(acc[3] + bias.w, 0.f));               \
        }                                                                         \
        xb0 = nx.v[0]; xb1 = nx.v[1];                                             \
    }

    PHASE(0, b1);   // x1 = relu(E @ w1 + b1)   (w1 standard, E standard)
    PHASE(1, b2);   // x2 = relu(x1 @ w2 + b2)  (w2 permuted)
#undef PHASE

    // ---- phase 3: gate/shift GEMMs (Bw/Cw permuted) + message + store ----
#pragma unroll
    for (int m = 0; m < 4; ++m) {
        f32x4 gb = {0.f, 0.f, 0.f, 0.f};
        gb = __builtin_amdgcn_mfma_f32_16x16x32_bf16(wf[2][0][m], xb0, gb, 0, 0, 0);
        gb = __builtin_amdgcn_mfma_f32_16x16x32_bf16(wf[2][1][m], xb1, gb, 0, 0, 0);
        f32x4 sc = {0.f, 0.f, 0.f, 0.f};
        sc = __builtin_amdgcn_mfma_f32_16x16x32_bf16(wf[3][0][m], xb0, sc, 0, 0, 0);
        sc = __builtin_amdgcn_mfma_f32_16x16x32_bf16(wf[3][1][m], xb1, sc, 0, 0, 0);
        const float4 biasB = *(const float4*)(Bb + 16 * m + 4 * hi);
        const float4 biasC = *(const float4*)(Cb + 16 * m + 4 * hi);
        const float* vp = (const float*)&vpre[m];
        const float* bBp = (const float*)&biasB;
        const float* bCp = (const float*)&biasC;
        float mm[4];
#pragma unroll
        for (int r = 0; r < 4; ++r) {
            const float gate = 1.f / (1.f + __expf(-(gb[r] + bBp[r])));
            float q = fmaf(gate, vp[r], sc[r] + bCp[r]);
            q = fmaxf(q, EPS);
            mm[r] = q * q;
        }
        uint2 p;
        p.x = pack2bf(mm[0], mm[1]);
        p.y = pack2bf(mm[2], mm[3]);
        *(uint2*)((unsigned short*)msg + (size_t)pos * DIM + 16 * m + 4 * hi) = p;
    }
}

// ---------------------------------------------------------------------------
// Aggregate: one wave per node; 8 edges per trip via uint4, shfl_xor reduce.
// ---------------------------------------------------------------------------
__global__ __launch_bounds__(256) void aggregate_kernel(
    const __hip_bfloat16* __restrict__ msg,
    const int* __restrict__ lofs, const int* __restrict__ bbase,
    const int* __restrict__ cnt,
    float* __restrict__ out)
{
    const int n = (blockIdx.x * 256 + threadIdx.x) >> 6;
    const int lane = threadIdx.x & 63;
    if (n >= N_NODES) return;
    const int start = lofs[n] + bbase[n >> 10];
    const int deg = cnt[n];
    const int rowg = lane >> 3;
    const int dblk = lane & 7;

    const unsigned short* bp = (const unsigned short*)msg + (size_t)start * DIM + dblk * 8;
    float acc0 = 0.f, acc1 = 0.f, acc2 = 0.f, acc3 = 0.f;
    float acc4 = 0.f, acc5 = 0.f, acc6 = 0.f, acc7 = 0.f;
    for (int i = 0; i < deg; i += 8) {
        const int r = i + rowg;
        if (r < deg) {
            const uint4 u = *(const uint4*)(bp + (size_t)r * DIM);
            acc0 += __uint_as_float(u.x << 16);
            acc1 += __uint_as_float(u.x & 0xffff0000u);
            acc2 += __uint_as_float(u.y << 16);
            acc3 += __uint_as_float(u.y & 0xffff0000u);
            acc4 += __uint_as_float(u.z << 16);
            acc5 += __uint_as_float(u.z & 0xffff0000u);
            acc6 += __uint_as_float(u.w << 16);
            acc7 += __uint_as_float(u.w & 0xffff0000u);
        }
    }
#pragma unroll
    for (int m = 8; m <= 32; m <<= 1) {
        acc0 += __shfl_xor(acc0, m, 64);
        acc1 += __shfl_xor(acc1, m, 64);
        acc2 += __shfl_xor(acc2, m, 64);
        acc3 += __shfl_xor(acc3, m, 64);
        acc4 += __shfl_xor(acc4, m, 64);
        acc5 += __shfl_xor(acc5, m, 64);
        acc6 += __shfl_xor(acc6, m, 64);
        acc7 += __shfl_xor(acc7, m, 64);
    }
    if (rowg == 0) {
        const float dinv = (deg > 0) ? 1.0f / (float)deg : 0.0f;
        float4 o0, o1;
        o0.x = sqrtf(acc0 * dinv); o0.y = sqrtf(acc1 * dinv);
        o0.z = sqrtf(acc2 * dinv); o0.w = sqrtf(acc3 * dinv);
        o1.x = sqrtf(acc4 * dinv); o1.y = sqrtf(acc5 * dinv);
        o1.z = sqrtf(acc6 * dinv); o1.w = sqrtf(acc7 * dinv);
        float4* op = (float4*)(out + (size_t)n * DIM + dblk * 8);
        op[0] = o0;
        op[1] = o1;
    }
}

extern "C" void kernel_launch(void* const* d_in, const int* in_sizes, int n_in,
                              void* d_out, int out_size, void* d_ws, size_t ws_size,
                              hipStream_t stream) {
    const float* V   = (const float*)d_in[0];
    const float* E   = (const float*)d_in[1];
    const int*   src = (const int*)d_in[2];
    const int*   dst = (const int*)d_in[3];
    const float* w1  = (const float*)d_in[4];
    const float* b1  = (const float*)d_in[5];
    const float* w2  = (const float*)d_in[6];
    const float* b2  = (const float*)d_in[7];
    const float* Bw  = (const float*)d_in[8];
    const float* Bb  = (const float*)d_in[9];
    const float* Cw  = (const float*)d_in[10];
    const float* Cb  = (const float*)d_in[11];
    const float* pAw = (const float*)d_in[12];
    const float* pAb = (const float*)d_in[13];
    const float* pBw = (const float*)d_in[14];
    const float* pBb = (const float*)d_in[15];

    float* out = (float*)d_out;

    // workspace layout
    char* p = (char*)d_ws;
    float* Vp = (float*)p;                    p += (size_t)N_NODES * DIM * sizeof(float);
    __hip_bfloat16* msg = (__hip_bfloat16*)p; p += (size_t)N_EDGES * DIM * 2;
    int* cnt  = (int*)p; p += (size_t)50176 * 4;
    int* lofs = (int*)p; p += (size_t)50176 * 4;
    int* rank = (int*)p; p += (size_t)N_EDGES * 4;
    unsigned short* wbf = (unsigned short*)p; p += (size_t)6 * 4096 * 2;
    int* btot  = (int*)p; p += (size_t)64 * 4;
    int* bbase = (int*)p; p += (size_t)64 * 4;

    prep_kernel<<<6 + SCANA_BLOCKS, 256, 0, stream>>>(w1, w2, Bw, Cw, pAw, pBw, wbf, cnt);
    hist_kernel<<<N_EDGES / 256, 256, 0, stream>>>(dst, cnt, rank);
    node_kernel<<<(N_NODES + 127) / 128, 256, 0, stream>>>(V, wbf, pAb, pBb, Vp);
    scanA_kernel<<<SCANA_BLOCKS, 256, 0, stream>>>(cnt, lofs, btot);
    scanB_kernel<<<1, 64, 0, stream>>>(btot, bbase);
    edge_kernel<<<N_EDGES / 64, 256, 0, stream>>>(E, src, dst, rank, lofs, bbase, wbf,
                                                  b1, b2, Bb, Cb, Vp, msg);
    aggregate_kernel<<<(N_NODES * 64 + 255) / 256, 256, 0, stream>>>(msg, lofs, bbase, cnt, out);
}

// Round 12
// 228.587 us; speedup vs baseline: 1.0890x; 1.0890x over previous
//
#include <hip/hip_runtime.h>
#include <hip/hip_bf16.h>
#include <math.h>

// Problem constants (match reference)
#define N_NODES 50000
#define N_EDGES 800000
#define DIM 64
#define NEG_SLOPE 0.2f
#define EPS 1e-5f

typedef __attribute__((ext_vector_type(8))) short short8v;  // 8 bf16 (4 VGPRs)
typedef __attribute__((ext_vector_type(4))) float f32x4;    // MFMA accumulator

union frag_u { unsigned u[8]; short8v v[2]; };

__device__ __forceinline__ float lrelu(float v) { return fmaxf(v, NEG_SLOPE * v); }

__device__ __forceinline__ unsigned short bfbits(float v) {
    return __bfloat16_as_ushort(__float2bfloat16(v));
}
// packed pair f32->bf16
__device__ __forceinline__ unsigned pack2bf(float a, float b) {
    union { __hip_bfloat162 h; unsigned u; } cvt;
    cvt.h = __float22bfloat162_rn(make_float2(a, b));
    return cvt.u;
}

// Swizzled byte offset into a 128-byte-stride LDS tile (node_kernel only).
__device__ __forceinline__ unsigned swz(unsigned row, unsigned byteInRow) {
    return row * 128u + (byteInRow ^ ((row & 7u) << 4));
}

#define LDS_BUF 16384  // 128 rows x 128 bytes

// Fragment-layout weight store: matrix m, entry idx=(ks*4+g)*64+col holds
// short8 {bf16(W[k(ks,g,j)][col]), j=0..7}, used as MFMA A-operand (W^T).
// Matrices 0 (w1), 4 (pAw), 5 (pBw): standard k = 32ks+8g+j.
// Matrices 1 (w2), 2 (Bw), 3 (Cw): PERMUTED k = pi(ks,g,j) =
//   16*(2ks + (j>>2)) + 4g + (j&3)
// so the previous phase's C-layout output IS the next phase's B-fragment
// after cvt_pk packing (verified numerically in r9/r11: absmax identical).
#define WFRAG_ENTRIES 512   // 2ks * 4g * 64col per matrix

#define SCANA_BLOCKS 49     // 49*1024 = 50176 >= 50000

// ---------------------------------------------------------------------------
// prep: blocks 0..5 convert weight matrices fp32 -> fragment bf16;
//       blocks 6..54 zero cnt (absorbs the memset dispatch)
// ---------------------------------------------------------------------------
__global__ __launch_bounds__(256) void prep_kernel(
    const float* __restrict__ w1, const float* __restrict__ w2,
    const float* __restrict__ Bw, const float* __restrict__ Cw,
    const float* __restrict__ pAw, const float* __restrict__ pBw,
    unsigned short* __restrict__ wbf, int* __restrict__ cnt)
{
    const int t = threadIdx.x;
    if (blockIdx.x >= 6) {
        const int idx = (blockIdx.x - 6) * 1024 + t * 4;
        if (idx + 3 < N_NODES) {
            int4 z = {0, 0, 0, 0};
            *(int4*)(cnt + idx) = z;
        } else {
#pragma unroll
            for (int i = 0; i < 4; ++i)
                if (idx + i < N_NODES) cnt[idx + i] = 0;
        }
        return;
    }
    const float* W;
    switch (blockIdx.x) {
        case 0: W = w1; break;
        case 1: W = w2; break;
        case 2: W = Bw; break;
        case 3: W = Cw; break;
        case 4: W = pAw; break;
        default: W = pBw; break;
    }
    const bool permuted = (blockIdx.x >= 1 && blockIdx.x <= 3);
#pragma unroll
    for (int ii = 0; ii < 2; ++ii) {
        const int idx = t * 2 + ii;          // 0..511
        const int ks  = idx >> 8;
        const int g   = (idx >> 6) & 3;
        const int col = idx & 63;
        unsigned short* o = wbf + (size_t)blockIdx.x * 4096 + (size_t)idx * 8;
#pragma unroll
        for (int j = 0; j < 8; ++j) {
            const int k = permuted ? (16 * (2 * ks + (j >> 2)) + 4 * g + (j & 3))
                                   : (32 * ks + 8 * g + j);
            o[j] = bfbits(W[k * DIM + col]);
        }
    }
}

// fragment fetch helper (m = matrix id, ks = k-step)
__device__ __forceinline__ short8v wfrag(const unsigned short* wbf, int m, int ks,
                                         int g, int col) {
    return ((const short8v*)wbf)[m * WFRAG_ENTRIES + (ks * 4 + g) * 64 + col];
}

// ---------------------------------------------------------------------------
// Node pooling via MFMA (matrices 4,5 standard layout)
// ---------------------------------------------------------------------------
__global__ __launch_bounds__(256) void node_kernel(
    const float* __restrict__ V,
    const unsigned short* __restrict__ wbf,
    const float* __restrict__ pAb, const float* __restrict__ pBb,
    float* __restrict__ Vp)
{
    __shared__ __align__(16) unsigned char sm[2 * LDS_BUF];
    unsigned char* bufA = sm;
    unsigned char* bufB = sm + LDS_BUF;

    const int t    = threadIdx.x;
    const int w    = t >> 6;
    const int lane = t & 63;
    const int g    = lane >> 4;
    const int c    = lane & 15;
    const int col  = 16 * w + c;
    const unsigned colbyte = (unsigned)col * 2;
    const int base = blockIdx.x * 128;

    {
        const int row = t >> 1;
        const int n = base + row;
        if (n < N_NODES) {
            const float4* Vr = (const float4*)(V + (size_t)n * DIM + (t & 1) * 32);
#pragma unroll
            for (int ci = 0; ci < 4; ++ci) {
                float4 qa = Vr[2 * ci];
                float4 qb = Vr[2 * ci + 1];
                uint4 u;
                u.x = pack2bf(lrelu(qa.x), lrelu(qa.y));
                u.y = pack2bf(lrelu(qa.z), lrelu(qa.w));
                u.z = pack2bf(lrelu(qb.x), lrelu(qb.y));
                u.w = pack2bf(lrelu(qb.z), lrelu(qb.w));
                *(uint4*)(bufA + swz(row, (t & 1) * 64 + 16 * ci)) = u;
            }
        } else {
            uint4 z = {0u, 0u, 0u, 0u};
#pragma unroll
            for (int ci = 0; ci < 4; ++ci)
                *(uint4*)(bufA + swz(row, (t & 1) * 64 + 16 * ci)) = z;
        }
    }

    const short8v af0 = wfrag(wbf, 4, 0, g, col), af1 = wfrag(wbf, 4, 1, g, col);
    const short8v bf0 = wfrag(wbf, 5, 0, g, col), bf1 = wfrag(wbf, 5, 1, g, col);
    const float bbA = pAb[col], bbB = pBb[col];

    __syncthreads();

#pragma unroll
    for (int mt = 0; mt < 8; ++mt) {
        const int arow = mt * 16 + c;
        short8v a0 = *(const short8v*)(bufA + swz(arow, 16 * g));
        short8v a1 = *(const short8v*)(bufA + swz(arow, 64 + 16 * g));
        f32x4 acc = {0.f, 0.f, 0.f, 0.f};
        acc = __builtin_amdgcn_mfma_f32_16x16x32_bf16(a0, af0, acc, 0, 0, 0);
        acc = __builtin_amdgcn_mfma_f32_16x16x32_bf16(a1, af1, acc, 0, 0, 0);
#pragma unroll
        for (int r = 0; r < 4; ++r) {
            const float v = lrelu(acc[r] + bbA);
            *(unsigned short*)(bufB + swz(mt * 16 + 4 * g + r, colbyte)) = bfbits(v);
        }
    }
    __syncthreads();

#pragma unroll
    for (int mt = 0; mt < 8; ++mt) {
        const int arow = mt * 16 + c;
        short8v a0 = *(const short8v*)(bufB + swz(arow, 16 * g));
        short8v a1 = *(const short8v*)(bufB + swz(arow, 64 + 16 * g));
        f32x4 acc = {0.f, 0.f, 0.f, 0.f};
        acc = __builtin_amdgcn_mfma_f32_16x16x32_bf16(a0, bf0, acc, 0, 0, 0);
        acc = __builtin_amdgcn_mfma_f32_16x16x32_bf16(a1, bf1, acc, 0, 0, 0);
#pragma unroll
        for (int r = 0; r < 4; ++r) {
            const int n = base + mt * 16 + 4 * g + r;
            if (n < N_NODES) Vp[(size_t)n * DIM + col] = acc[r] + bbB;
        }
    }
}

// ---------------------------------------------------------------------------
// hist: per-dst count AND per-edge rank (slot within its node)
// ---------------------------------------------------------------------------
__global__ __launch_bounds__(256) void hist_kernel(
    const int* __restrict__ dst, int* __restrict__ cnt, int* __restrict__ rank)
{
    const int e = blockIdx.x * 256 + threadIdx.x;   // 800000 % 256 == 0
    rank[e] = atomicAdd(&cnt[dst[e]], 1);
}

// ---------------------------------------------------------------------------
// two-level scan
// ---------------------------------------------------------------------------
__global__ __launch_bounds__(256) void scanA_kernel(
    const int* __restrict__ cnt, int* __restrict__ lofs, int* __restrict__ btot)
{
    __shared__ int ts[256];
    const int t = threadIdx.x;
    const int nb = blockIdx.x * 1024 + t * 4;
    int4 c = {0, 0, 0, 0};
    if (nb + 3 < N_NODES) {
        c = *(const int4*)(cnt + nb);
    } else {
        if (nb + 0 < N_NODES) c.x = cnt[nb + 0];
        if (nb + 1 < N_NODES) c.y = cnt[nb + 1];
        if (nb + 2 < N_NODES) c.z = cnt[nb + 2];
        if (nb + 3 < N_NODES) c.w = cnt[nb + 3];
    }
    ts[t] = c.x + c.y + c.z + c.w;
    __syncthreads();
    for (int off = 1; off < 256; off <<= 1) {
        const int add = (t >= off) ? ts[t - off] : 0;
        __syncthreads();
        ts[t] += add;
        __syncthreads();
    }
    int4 o;
    o.x = (t == 0) ? 0 : ts[t - 1];
    o.y = o.x + c.x;
    o.z = o.y + c.y;
    o.w = o.z + c.z;
    if (nb + 3 < N_NODES) {
        *(int4*)(lofs + nb) = o;
    } else {
        if (nb + 0 < N_NODES) lofs[nb + 0] = o.x;
        if (nb + 1 < N_NODES) lofs[nb + 1] = o.y;
        if (nb + 2 < N_NODES) lofs[nb + 2] = o.z;
        if (nb + 3 < N_NODES) lofs[nb + 3] = o.w;
    }
    if (t == 255) btot[blockIdx.x] = ts[255];
}

__global__ __launch_bounds__(64) void scanB_kernel(
    const int* __restrict__ btot, int* __restrict__ bbase)
{
    const int t = threadIdx.x;    // one wave
    const int own = (t < SCANA_BLOCKS) ? btot[t] : 0;
    int v = own;
    for (int off = 1; off < 64; off <<= 1) {
        const int u = __shfl_up(v, off, 64);
        if (t >= off) v += u;
    }
    if (t < SCANA_BLOCKS) bbase[t] = v - own;   // exclusive
}

// ---------------------------------------------------------------------------
// ALL-REGISTER transposed-dual MFMA edge pipeline, ZERO LDS / barriers.
// FIX vs r11: (1) weight fragments PINNED in registers via asm "+v" after the
// load burst — the compiler can no longer sink/remat the loads to use sites
// (r11 failure: VGPR stayed 56, loads on per-phase critical path);
// (2) TWO 16-edge tiles per wave share the fragments — the load burst is
// amortized over 2x MFMA work and the dual chains give intra-wave ILP.
// ---------------------------------------------------------------------------
__global__ __launch_bounds__(256, 1) void edge_kernel(
    const float* __restrict__ E,
    const int* __restrict__ src, const int* __restrict__ dst,
    const int* __restrict__ rank,
    const int* __restrict__ lofs, const int* __restrict__ bbase,
    const unsigned short* __restrict__ wbf,
    const float* __restrict__ b1, const float* __restrict__ b2,
    const float* __restrict__ Bb, const float* __restrict__ Cb,
    const float* __restrict__ Vp,
    __hip_bfloat16* __restrict__ msg)
{
    const int t    = threadIdx.x;
    const int lane = t & 63;
    const int c    = lane & 15;
    const int hi   = lane >> 4;
    const int wbase = blockIdx.x * 128 + (t >> 6) * 32;  // wave's 32 edges
    const int e0 = wbase + c;
    const int e1 = wbase + 16 + c;

    // ---- early scattered loads: CSR slots, src, Vp gathers ----
    const int d0 = dst[e0], d1 = dst[e1];
    const int s0 = src[e0], s1 = src[e1];
    const int pos0 = lofs[d0] + bbase[d0 >> 10] + rank[e0];
    const int pos1 = lofs[d1] + bbase[d1 >> 10] + rank[e1];

    float4 vpre0[4], vpre1[4];
#pragma unroll
    for (int m = 0; m < 4; ++m) {
        vpre0[m] = *(const float4*)(Vp + (size_t)s0 * DIM + 16 * m + 4 * hi);
        vpre1[m] = *(const float4*)(Vp + (size_t)s1 * DIM + 16 * m + 4 * hi);
    }

    // ---- weight fragments: 32 independent b128 loads, then PIN ----
    short8v wf[4][2][4];   // [mat][ks][m] — all static indices (unrolled)
#pragma unroll
    for (int mat = 0; mat < 4; ++mat)
#pragma unroll
        for (int ks = 0; ks < 2; ++ks)
#pragma unroll
            for (int m = 0; m < 4; ++m)
                wf[mat][ks][m] = wfrag(wbf, mat, ks, hi, 16 * m + c);
#pragma unroll
    for (int mat = 0; mat < 4; ++mat)
#pragma unroll
        for (int ks = 0; ks < 2; ++ks)
#pragma unroll
            for (int m = 0; m < 4; ++m)
                asm volatile("" : "+v"(wf[mat][ks][m]));   // force residency

    // ---- E rows -> B-fragments (standard k order: k = 32ks + 8hi + j) ----
    short8v x0b0, x0b1, x1b0, x1b1;
    {
        const float* Ep0 = E + (size_t)e0 * DIM + 8 * hi;
        const float* Ep1 = E + (size_t)e1 * DIM + 8 * hi;
        const float4 qa0 = *(const float4*)(Ep0 + 0);
        const float4 qb0 = *(const float4*)(Ep0 + 4);
        const float4 qc0 = *(const float4*)(Ep0 + 32);
        const float4 qd0 = *(const float4*)(Ep0 + 36);
        const float4 qa1 = *(const float4*)(Ep1 + 0);
        const float4 qb1 = *(const float4*)(Ep1 + 4);
        const float4 qc1 = *(const float4*)(Ep1 + 32);
        const float4 qd1 = *(const float4*)(Ep1 + 36);
        frag_u f0, f1;
        f0.u[0] = pack2bf(qa0.x, qa0.y); f0.u[1] = pack2bf(qa0.z, qa0.w);
        f0.u[2] = pack2bf(qb0.x, qb0.y); f0.u[3] = pack2bf(qb0.z, qb0.w);
        f0.u[4] = pack2bf(qc0.x, qc0.y); f0.u[5] = pack2bf(qc0.z, qc0.w);
        f0.u[6] = pack2bf(qd0.x, qd0.y); f0.u[7] = pack2bf(qd0.z, qd0.w);
        f1.u[0] = pack2bf(qa1.x, qa1.y); f1.u[1] = pack2bf(qa1.z, qa1.w);
        f1.u[2] = pack2bf(qb1.x, qb1.y); f1.u[3] = pack2bf(qb1.z, qb1.w);
        f1.u[4] = pack2bf(qc1.x, qc1.y); f1.u[5] = pack2bf(qc1.z, qc1.w);
        f1.u[6] = pack2bf(qd1.x, qd1.y); f1.u[7] = pack2bf(qd1.z, qd1.w);
        x0b0 = f0.v[0]; x0b1 = f0.v[1];
        x1b0 = f1.v[0]; x1b1 = f1.v[1];
    }

    // One relu phase on both tiles: xb <- relu(W^T x + b). C-layout output
    // packs directly into next B-fragments (pi baked into next weights).
#define PHASE(MAT, BIASP)                                                         \
    {                                                                             \
        frag_u nx0, nx1;                                                          \
        _Pragma("unroll")                                                         \
        for (int m = 0; m < 4; ++m) {                                             \
            f32x4 a0 = {0.f, 0.f, 0.f, 0.f};                                      \
            a0 = __builtin_amdgcn_mfma_f32_16x16x32_bf16(wf[MAT][0][m], x0b0, a0, 0, 0, 0); \
            a0 = __builtin_amdgcn_mfma_f32_16x16x32_bf16(wf[MAT][1][m], x0b1, a0, 0, 0, 0); \
            f32x4 a1 = {0.f, 0.f, 0.f, 0.f};                                      \
            a1 = __builtin_amdgcn_mfma_f32_16x16x32_bf16(wf[MAT][0][m], x1b0, a1, 0, 0, 0); \
            a1 = __builtin_amdgcn_mfma_f32_16x16x32_bf16(wf[MAT][1][m], x1b1, a1, 0, 0, 0); \
            const float4 bias = *(const float4*)(BIASP + 16 * m + 4 * hi);        \
            nx0.u[2 * m]     = pack2bf(fmaxf(a0[0] + bias.x, 0.f),                \
                                       fmaxf(a0[1] + bias.y, 0.f));               \
            nx0.u[2 * m + 1] = pack2bf(fmaxf(a0[2] + bias.z, 0.f),                \
                                       fmaxf(a0[3] + bias.w, 0.f));               \
            nx1.u[2 * m]     = pack2bf(fmaxf(a1[0] + bias.x, 0.f),                \
                                       fmaxf(a1[1] + bias.y, 0.f));               \
            nx1.u[2 * m + 1] = pack2bf(fmaxf(a1[2] + bias.z, 0.f),                \
                                       fmaxf(a1[3] + bias.w, 0.f));               \
        }                                                                         \
        x0b0 = nx0.v[0]; x0b1 = nx0.v[1];                                         \
        x1b0 = nx1.v[0]; x1b1 = nx1.v[1];                                         \
    }

    PHASE(0, b1);   // x1 = relu(E @ w1 + b1)
    PHASE(1, b2);   // x2 = relu(x1 @ w2 + b2)
#undef PHASE

    // ---- phase 3: gate/shift GEMMs + message + store, both tiles ----
#pragma unroll
    for (int m = 0; m < 4; ++m) {
        f32x4 gb0 = {0.f, 0.f, 0.f, 0.f}, gb1 = {0.f, 0.f, 0.f, 0.f};
        gb0 = __builtin_amdgcn_mfma_f32_16x16x32_bf16(wf[2][0][m], x0b0, gb0, 0, 0, 0);
        gb0 = __builtin_amdgcn_mfma_f32_16x16x32_bf16(wf[2][1][m], x0b1, gb0, 0, 0, 0);
        gb1 = __builtin_amdgcn_mfma_f32_16x16x32_bf16(wf[2][0][m], x1b0, gb1, 0, 0, 0);
        gb1 = __builtin_amdgcn_mfma_f32_16x16x32_bf16(wf[2][1][m], x1b1, gb1, 0, 0, 0);
        f32x4 sc0 = {0.f, 0.f, 0.f, 0.f}, sc1 = {0.f, 0.f, 0.f, 0.f};
        sc0 = __builtin_amdgcn_mfma_f32_16x16x32_bf16(wf[3][0][m], x0b0, sc0, 0, 0, 0);
        sc0 = __builtin_amdgcn_mfma_f32_16x16x32_bf16(wf[3][1][m], x0b1, sc0, 0, 0, 0);
        sc1 = __builtin_amdgcn_mfma_f32_16x16x32_bf16(wf[3][0][m], x1b0, sc1, 0, 0, 0);
        sc1 = __builtin_amdgcn_mfma_f32_16x16x32_bf16(wf[3][1][m], x1b1, sc1, 0, 0, 0);
        const float4 biasB = *(const float4*)(Bb + 16 * m + 4 * hi);
        const float4 biasC = *(const float4*)(Cb + 16 * m + 4 * hi);
        const float* vp0 = (const float*)&vpre0[m];
        const float* vp1 = (const float*)&vpre1[m];
        const float* bBp = (const float*)&biasB;
        const float* bCp = (const float*)&biasC;
        float m0[4], m1[4];
#pragma unroll
        for (int r = 0; r < 4; ++r) {
            const float g0 = 1.f / (1.f + __expf(-(gb0[r] + bBp[r])));
            const float g1 = 1.f / (1.f + __expf(-(gb1[r] + bBp[r])));
            float q0 = fmaf(g0, vp0[r], sc0[r] + bCp[r]);
            float q1 = fmaf(g1, vp1[r], sc1[r] + bCp[r]);
            q0 = fmaxf(q0, EPS); m0[r] = q0 * q0;
            q1 = fmaxf(q1, EPS); m1[r] = q1 * q1;
        }
        uint2 p0, p1;
        p0.x = pack2bf(m0[0], m0[1]); p0.y = pack2bf(m0[2], m0[3]);
        p1.x = pack2bf(m1[0], m1[1]); p1.y = pack2bf(m1[2], m1[3]);
        *(uint2*)((unsigned short*)msg + (size_t)pos0 * DIM + 16 * m + 4 * hi) = p0;
        *(uint2*)((unsigned short*)msg + (size_t)pos1 * DIM + 16 * m + 4 * hi) = p1;
    }
}

// ---------------------------------------------------------------------------
// Aggregate: one wave per node; 8 edges per trip via uint4, shfl_xor reduce.
// ---------------------------------------------------------------------------
__global__ __launch_bounds__(256) void aggregate_kernel(
    const __hip_bfloat16* __restrict__ msg,
    const int* __restrict__ lofs, const int* __restrict__ bbase,
    const int* __restrict__ cnt,
    float* __restrict__ out)
{
    const int n = (blockIdx.x * 256 + threadIdx.x) >> 6;
    const int lane = threadIdx.x & 63;
    if (n >= N_NODES) return;
    const int start = lofs[n] + bbase[n >> 10];
    const int deg = cnt[n];
    const int rowg = lane >> 3;
    const int dblk = lane & 7;

    const unsigned short* bp = (const unsigned short*)msg + (size_t)start * DIM + dblk * 8;
    float acc0 = 0.f, acc1 = 0.f, acc2 = 0.f, acc3 = 0.f;
    float acc4 = 0.f, acc5 = 0.f, acc6 = 0.f, acc7 = 0.f;
    for (int i = 0; i < deg; i += 8) {
        const int r = i + rowg;
        if (r < deg) {
            const uint4 u = *(const uint4*)(bp + (size_t)r * DIM);
            acc0 += __uint_as_float(u.x << 16);
            acc1 += __uint_as_float(u.x & 0xffff0000u);
            acc2 += __uint_as_float(u.y << 16);
            acc3 += __uint_as_float(u.y & 0xffff0000u);
            acc4 += __uint_as_float(u.z << 16);
            acc5 += __uint_as_float(u.z & 0xffff0000u);
            acc6 += __uint_as_float(u.w << 16);
            acc7 += __uint_as_float(u.w & 0xffff0000u);
        }
    }
#pragma unroll
    for (int m = 8; m <= 32; m <<= 1) {
        acc0 += __shfl_xor(acc0, m, 64);
        acc1 += __shfl_xor(acc1, m, 64);
        acc2 += __shfl_xor(acc2, m, 64);
        acc3 += __shfl_xor(acc3, m, 64);
        acc4 += __shfl_xor(acc4, m, 64);
        acc5 += __shfl_xor(acc5, m, 64);
        acc6 += __shfl_xor(acc6, m, 64);
        acc7 += __shfl_xor(acc7, m, 64);
    }
    if (rowg == 0) {
        const float dinv = (deg > 0) ? 1.0f / (float)deg : 0.0f;
        float4 o0, o1;
        o0.x = sqrtf(acc0 * dinv); o0.y = sqrtf(acc1 * dinv);
        o0.z = sqrtf(acc2 * dinv); o0.w = sqrtf(acc3 * dinv);
        o1.x = sqrtf(acc4 * dinv); o1.y = sqrtf(acc5 * dinv);
        o1.z = sqrtf(acc6 * dinv); o1.w = sqrtf(acc7 * dinv);
        float4* op = (float4*)(out + (size_t)n * DIM + dblk * 8);
        op[0] = o0;
        op[1] = o1;
    }
}

extern "C" void kernel_launch(void* const* d_in, const int* in_sizes, int n_in,
                              void* d_out, int out_size, void* d_ws, size_t ws_size,
                              hipStream_t stream) {
    const float* V   = (const float*)d_in[0];
    const float* E   = (const float*)d_in[1];
    const int*   src = (const int*)d_in[2];
    const int*   dst = (const int*)d_in[3];
    const float* w1  = (const float*)d_in[4];
    const float* b1  = (const float*)d_in[5];
    const float* w2  = (const float*)d_in[6];
    const float* b2  = (const float*)d_in[7];
    const float* Bw  = (const float*)d_in[8];
    const float* Bb  = (const float*)d_in[9];
    const float* Cw  = (const float*)d_in[10];
    const float* Cb  = (const float*)d_in[11];
    const float* pAw = (const float*)d_in[12];
    const float* pAb = (const float*)d_in[13];
    const float* pBw = (const float*)d_in[14];
    const float* pBb = (const float*)d_in[15];

    float* out = (float*)d_out;

    // workspace layout
    char* p = (char*)d_ws;
    float* Vp = (float*)p;                    p += (size_t)N_NODES * DIM * sizeof(float);
    __hip_bfloat16* msg = (__hip_bfloat16*)p; p += (size_t)N_EDGES * DIM * 2;
    int* cnt  = (int*)p; p += (size_t)50176 * 4;
    int* lofs = (int*)p; p += (size_t)50176 * 4;
    int* rank = (int*)p; p += (size_t)N_EDGES * 4;
    unsigned short* wbf = (unsigned short*)p; p += (size_t)6 * 4096 * 2;
    int* btot  = (int*)p; p += (size_t)64 * 4;
    int* bbase = (int*)p; p += (size_t)64 * 4;

    prep_kernel<<<6 + SCANA_BLOCKS, 256, 0, stream>>>(w1, w2, Bw, Cw, pAw, pBw, wbf, cnt);
    hist_kernel<<<N_EDGES / 256, 256, 0, stream>>>(dst, cnt, rank);
    node_kernel<<<(N_NODES + 127) / 128, 256, 0, stream>>>(V, wbf, pAb, pBb, Vp);
    scanA_kernel<<<SCANA_BLOCKS, 256, 0, stream>>>(cnt, lofs, btot);
    scanB_kernel<<<1, 64, 0, stream>>>(btot, bbase);
    edge_kernel<<<N_EDGES / 128, 256, 0, stream>>>(E, src, dst, rank, lofs, bbase, wbf,
                                                   b1, b2, Bb, Cb, Vp, msg);
    aggregate_kernel<<<(N_NODES * 64 + 255) / 256, 256, 0, stream>>>(msg, lofs, bbase, cnt, out);
}

// Round 13
// 195.916 us; speedup vs baseline: 1.2706x; 1.1668x over previous
//
#include <hip/hip_runtime.h>
#include <hip/hip_bf16.h>
#include <math.h>

// Problem constants (match reference)
#define N_NODES 50000
#define N_EDGES 800000
#define DIM 64
#define NEG_SLOPE 0.2f
#define EPS 1e-5f

typedef __attribute__((ext_vector_type(8))) short short8v;  // 8 bf16 (4 VGPRs)
typedef __attribute__((ext_vector_type(4))) float f32x4;    // MFMA accumulator

__device__ __forceinline__ float lrelu(float v) { return fmaxf(v, NEG_SLOPE * v); }

__device__ __forceinline__ unsigned short bfbits(float v) {
    return __bfloat16_as_ushort(__float2bfloat16(v));
}
// packed pair f32->bf16
__device__ __forceinline__ unsigned pack2bf(float a, float b) {
    union { __hip_bfloat162 h; unsigned u; } cvt;
    cvt.h = __float22bfloat162_rn(make_float2(a, b));
    return cvt.u;
}

// Swizzled byte offset into a 128-byte-stride LDS tile (T2: byte ^= (row&7)<<4).
__device__ __forceinline__ unsigned swz(unsigned row, unsigned byteInRow) {
    return row * 128u + (byteInRow ^ ((row & 7u) << 4));
}

#define LDS_BUF 16384  // 128 rows x 128 bytes

// Fragment-layout weight store: matrix m, entry idx=(ks*4+g)*64+col holds
// short8 {bf16(W[(32ks+8g+j)*64+col]), j=0..7}. One b128 load per fragment.
#define WFRAG_ENTRIES 512   // 2ks * 4g * 64col per matrix

#define SCANA_BLOCKS 49     // 49*1024 = 50176 >= 50000

// ---------------------------------------------------------------------------
// prep: blocks 0..5 convert weight matrices fp32 -> fragment bf16;
//       blocks 6..54 zero cnt (absorbs the memset dispatch)
// ---------------------------------------------------------------------------
__global__ __launch_bounds__(256) void prep_kernel(
    const float* __restrict__ w1, const float* __restrict__ w2,
    const float* __restrict__ Bw, const float* __restrict__ Cw,
    const float* __restrict__ pAw, const float* __restrict__ pBw,
    unsigned short* __restrict__ wbf, int* __restrict__ cnt)
{
    const int t = threadIdx.x;
    if (blockIdx.x >= 6) {
        const int idx = (blockIdx.x - 6) * 1024 + t * 4;
        if (idx + 3 < N_NODES) {
            int4 z = {0, 0, 0, 0};
            *(int4*)(cnt + idx) = z;
        } else {
#pragma unroll
            for (int i = 0; i < 4; ++i)
                if (idx + i < N_NODES) cnt[idx + i] = 0;
        }
        return;
    }
    const float* W;
    switch (blockIdx.x) {
        case 0: W = w1; break;
        case 1: W = w2; break;
        case 2: W = Bw; break;
        case 3: W = Cw; break;
        case 4: W = pAw; break;
        default: W = pBw; break;
    }
#pragma unroll
    for (int ii = 0; ii < 2; ++ii) {
        const int idx = t * 2 + ii;          // 0..511
        const int ks  = idx >> 8;
        const int g   = (idx >> 6) & 3;
        const int col = idx & 63;
        unsigned short* o = wbf + (size_t)blockIdx.x * 4096 + (size_t)idx * 8;
#pragma unroll
        for (int j = 0; j < 8; ++j)
            o[j] = bfbits(W[(32 * ks + 8 * g + j) * DIM + col]);
    }
}

// fragment fetch helper (m = matrix id, ks = k-step)
__device__ __forceinline__ short8v wfrag(const unsigned short* wbf, int m, int ks,
                                         int g, int col) {
    return ((const short8v*)wbf)[m * WFRAG_ENTRIES + (ks * 4 + g) * 64 + col];
}

// ---------------------------------------------------------------------------
// Node pooling via MFMA: Vp = lrelu(lrelu(V)@pAw+pAb)@pBw+pBb
// ---------------------------------------------------------------------------
__global__ __launch_bounds__(256) void node_kernel(
    const float* __restrict__ V,
    const unsigned short* __restrict__ wbf,
    const float* __restrict__ pAb, const float* __restrict__ pBb,
    float* __restrict__ Vp)
{
    __shared__ __align__(16) unsigned char sm[2 * LDS_BUF];
    unsigned char* bufA = sm;
    unsigned char* bufB = sm + LDS_BUF;

    const int t    = threadIdx.x;
    const int w    = t >> 6;
    const int lane = t & 63;
    const int g    = lane >> 4;
    const int c    = lane & 15;
    const int col  = 16 * w + c;
    const unsigned colbyte = (unsigned)col * 2;
    const int base = blockIdx.x * 128;

    {
        const int row = t >> 1;
        const int n = base + row;
        if (n < N_NODES) {
            const float4* Vr = (const float4*)(V + (size_t)n * DIM + (t & 1) * 32);
#pragma unroll
            for (int ci = 0; ci < 4; ++ci) {
                float4 qa = Vr[2 * ci];
                float4 qb = Vr[2 * ci + 1];
                uint4 u;
                u.x = pack2bf(lrelu(qa.x), lrelu(qa.y));
                u.y = pack2bf(lrelu(qa.z), lrelu(qa.w));
                u.z = pack2bf(lrelu(qb.x), lrelu(qb.y));
                u.w = pack2bf(lrelu(qb.z), lrelu(qb.w));
                *(uint4*)(bufA + swz(row, (t & 1) * 64 + 16 * ci)) = u;
            }
        } else {
            uint4 z = {0u, 0u, 0u, 0u};
#pragma unroll
            for (int ci = 0; ci < 4; ++ci)
                *(uint4*)(bufA + swz(row, (t & 1) * 64 + 16 * ci)) = z;
        }
    }

    const short8v af0 = wfrag(wbf, 4, 0, g, col), af1 = wfrag(wbf, 4, 1, g, col);
    const short8v bf0 = wfrag(wbf, 5, 0, g, col), bf1 = wfrag(wbf, 5, 1, g, col);
    const float bbA = pAb[col], bbB = pBb[col];

    __syncthreads();

#pragma unroll
    for (int mt = 0; mt < 8; ++mt) {
        const int arow = mt * 16 + c;
        short8v a0 = *(const short8v*)(bufA + swz(arow, 16 * g));
        short8v a1 = *(const short8v*)(bufA + swz(arow, 64 + 16 * g));
        f32x4 acc = {0.f, 0.f, 0.f, 0.f};
        acc = __builtin_amdgcn_mfma_f32_16x16x32_bf16(a0, af0, acc, 0, 0, 0);
        acc = __builtin_amdgcn_mfma_f32_16x16x32_bf16(a1, af1, acc, 0, 0, 0);
#pragma unroll
        for (int r = 0; r < 4; ++r) {
            const float v = lrelu(acc[r] + bbA);
            *(unsigned short*)(bufB + swz(mt * 16 + 4 * g + r, colbyte)) = bfbits(v);
        }
    }
    __syncthreads();

#pragma unroll
    for (int mt = 0; mt < 8; ++mt) {
        const int arow = mt * 16 + c;
        short8v a0 = *(const short8v*)(bufB + swz(arow, 16 * g));
        short8v a1 = *(const short8v*)(bufB + swz(arow, 64 + 16 * g));
        f32x4 acc = {0.f, 0.f, 0.f, 0.f};
        acc = __builtin_amdgcn_mfma_f32_16x16x32_bf16(a0, bf0, acc, 0, 0, 0);
        acc = __builtin_amdgcn_mfma_f32_16x16x32_bf16(a1, bf1, acc, 0, 0, 0);
#pragma unroll
        for (int r = 0; r < 4; ++r) {
            const int n = base + mt * 16 + 4 * g + r;
            if (n < N_NODES) Vp[(size_t)n * DIM + col] = acc[r] + bbB;
        }
    }
}

// ---------------------------------------------------------------------------
// hist: per-dst count AND per-edge rank (slot within its node)
// ---------------------------------------------------------------------------
__global__ __launch_bounds__(256) void hist_kernel(
    const int* __restrict__ dst, int* __restrict__ cnt, int* __restrict__ rank)
{
    const int e = blockIdx.x * 256 + threadIdx.x;   // 800000 % 256 == 0
    rank[e] = atomicAdd(&cnt[dst[e]], 1);
}

// ---------------------------------------------------------------------------
// scanA: per-1024-node block exclusive scan (lofs) + block total (btot)
// ---------------------------------------------------------------------------
__global__ __launch_bounds__(256) void scanA_kernel(
    const int* __restrict__ cnt, int* __restrict__ lofs, int* __restrict__ btot)
{
    __shared__ int ts[256];
    const int t = threadIdx.x;
    const int nb = blockIdx.x * 1024 + t * 4;
    int4 c = {0, 0, 0, 0};
    if (nb + 3 < N_NODES) {
        c = *(const int4*)(cnt + nb);
    } else {
        if (nb + 0 < N_NODES) c.x = cnt[nb + 0];
        if (nb + 1 < N_NODES) c.y = cnt[nb + 1];
        if (nb + 2 < N_NODES) c.z = cnt[nb + 2];
        if (nb + 3 < N_NODES) c.w = cnt[nb + 3];
    }
    ts[t] = c.x + c.y + c.z + c.w;
    __syncthreads();
    for (int off = 1; off < 256; off <<= 1) {
        const int add = (t >= off) ? ts[t - off] : 0;
        __syncthreads();
        ts[t] += add;
        __syncthreads();
    }
    int4 o;
    o.x = (t == 0) ? 0 : ts[t - 1];
    o.y = o.x + c.x;
    o.z = o.y + c.y;
    o.w = o.z + c.z;
    if (nb + 3 < N_NODES) {
        *(int4*)(lofs + nb) = o;
    } else {
        if (nb + 0 < N_NODES) lofs[nb + 0] = o.x;
        if (nb + 1 < N_NODES) lofs[nb + 1] = o.y;
        if (nb + 2 < N_NODES) lofs[nb + 2] = o.z;
        if (nb + 3 < N_NODES) lofs[nb + 3] = o.w;
    }
    if (t == 255) btot[blockIdx.x] = ts[255];
}

// ---------------------------------------------------------------------------
// fixup: block b adds prefix(btot[0..b)) to its 1024-node slice of lofs,
// making lofs the FINAL global CSR offset array (single-load consumers).
// ---------------------------------------------------------------------------
__global__ __launch_bounds__(256) void fixup_kernel(
    const int* __restrict__ btot, int* __restrict__ lofs)
{
    __shared__ int base_s;
    if (threadIdx.x < 64) {
        // wave-parallel exclusive prefix: sum btot[i] for i < blockIdx.x
        int v = (threadIdx.x < blockIdx.x) ? btot[threadIdx.x] : 0;
#pragma unroll
        for (int m = 1; m < 64; m <<= 1) v += __shfl_xor(v, m, 64);
        if (threadIdx.x == 0) base_s = v;
    }
    __syncthreads();
    const int base = base_s;
    const int idx = blockIdx.x * 1024 + threadIdx.x * 4;
    if (idx + 3 < N_NODES) {
        int4 v = *(int4*)(lofs + idx);
        v.x += base; v.y += base; v.z += base; v.w += base;
        *(int4*)(lofs + idx) = v;
    } else {
#pragma unroll
        for (int i = 0; i < 4; ++i)
            if (idx + i < N_NODES) lofs[idx + i] += base;
    }
}

// ---------------------------------------------------------------------------
// MFMA edge pipeline (r6 structure — best measured at 122 us).
// Block = 128 edges, 256 threads = 4 waves; fragment-layout weights (b128),
// Vp gather prefetched to registers; CSR slot = SINGLE lofs load + rank,
// staged in LDS by 128 threads (r6-measured fastest variant).
// ---------------------------------------------------------------------------
__global__ __launch_bounds__(256) void edge_kernel(
    const float* __restrict__ E,
    const int* __restrict__ src, const int* __restrict__ dst,
    const int* __restrict__ rank, const int* __restrict__ offs,
    const unsigned short* __restrict__ wbf,
    const float* __restrict__ b1, const float* __restrict__ b2,
    const float* __restrict__ Bb, const float* __restrict__ Cb,
    const float* __restrict__ Vp,
    __hip_bfloat16* __restrict__ msg)
{
    __shared__ __align__(16) unsigned char sm[2 * LDS_BUF + 128 * 4];
    unsigned char* bufA = sm;
    unsigned char* bufB = sm + LDS_BUF;
    int* eposv = (int*)(sm + 2 * LDS_BUF);

    const int t    = threadIdx.x;
    const int w    = t >> 6;
    const int lane = t & 63;
    const int g    = lane >> 4;
    const int c    = lane & 15;
    const int col  = 16 * w + c;
    const unsigned colbyte = (unsigned)col * 2;
    const int base = blockIdx.x * 128;

    // ---- CSR slot via LDS (128 staging threads own the scattered chain) ----
    if (t < 128) {
        eposv[t] = offs[dst[base + t]] + rank[base + t];
    }

    // ---- Vp gather prefetch: 32 independent chains, in flight during GEMMs
    float vpre[32];
#pragma unroll
    for (int mt = 0; mt < 8; ++mt) {
#pragma unroll
        for (int r = 0; r < 4; ++r) {
            const int sv = src[base + mt * 16 + 4 * g + r];
            vpre[mt * 4 + r] = Vp[(size_t)sv * DIM + col];
        }
    }

    // ---- stage E tile (fp32 -> bf16, swizzled) ----
    {
        const int row = t >> 1;
        const float4* Ep = (const float4*)(E + (size_t)(base + row) * DIM + (t & 1) * 32);
#pragma unroll
        for (int ci = 0; ci < 4; ++ci) {
            float4 qa = Ep[2 * ci];
            float4 qb = Ep[2 * ci + 1];
            uint4 u;
            u.x = pack2bf(qa.x, qa.y); u.y = pack2bf(qa.z, qa.w);
            u.z = pack2bf(qb.x, qb.y); u.w = pack2bf(qb.z, qb.w);
            *(uint4*)(bufA + swz(row, (t & 1) * 64 + 16 * ci)) = u;
        }
    }

    // ---- weight fragments: one b128 load each ----
    const short8v w1f0 = wfrag(wbf, 0, 0, g, col), w1f1 = wfrag(wbf, 0, 1, g, col);
    const short8v w2f0 = wfrag(wbf, 1, 0, g, col), w2f1 = wfrag(wbf, 1, 1, g, col);
    const short8v bwf0 = wfrag(wbf, 2, 0, g, col), bwf1 = wfrag(wbf, 2, 1, g, col);
    const short8v cwf0 = wfrag(wbf, 3, 0, g, col), cwf1 = wfrag(wbf, 3, 1, g, col);
    const float bb1 = b1[col], bb2 = b2[col], bbB = Bb[col], bbC = Cb[col];

    __syncthreads();

    // ---- layer 1: x1 = relu(E @ w1 + b1) : bufA -> bufB ----
#pragma unroll
    for (int mt = 0; mt < 8; ++mt) {
        const int arow = mt * 16 + c;
        short8v a0 = *(const short8v*)(bufA + swz(arow, 16 * g));
        short8v a1 = *(const short8v*)(bufA + swz(arow, 64 + 16 * g));
        f32x4 acc = {0.f, 0.f, 0.f, 0.f};
        acc = __builtin_amdgcn_mfma_f32_16x16x32_bf16(a0, w1f0, acc, 0, 0, 0);
        acc = __builtin_amdgcn_mfma_f32_16x16x32_bf16(a1, w1f1, acc, 0, 0, 0);
#pragma unroll
        for (int r = 0; r < 4; ++r) {
            const float v = fmaxf(acc[r] + bb1, 0.f);
            *(unsigned short*)(bufB + swz(mt * 16 + 4 * g + r, colbyte)) = bfbits(v);
        }
    }
    __syncthreads();

    // ---- layer 2: x2 = relu(x1 @ w2 + b2) : bufB -> bufA ----
#pragma unroll
    for (int mt = 0; mt < 8; ++mt) {
        const int arow = mt * 16 + c;
        short8v a0 = *(const short8v*)(bufB + swz(arow, 16 * g));
        short8v a1 = *(const short8v*)(bufB + swz(arow, 64 + 16 * g));
        f32x4 acc = {0.f, 0.f, 0.f, 0.f};
        acc = __builtin_amdgcn_mfma_f32_16x16x32_bf16(a0, w2f0, acc, 0, 0, 0);
        acc = __builtin_amdgcn_mfma_f32_16x16x32_bf16(a1, w2f1, acc, 0, 0, 0);
#pragma unroll
        for (int r = 0; r < 4; ++r) {
            const float v = fmaxf(acc[r] + bb2, 0.f);
            *(unsigned short*)(bufA + swz(mt * 16 + 4 * g + r, colbyte)) = bfbits(v);
        }
    }
    __syncthreads();

    // ---- gate + shift GEMMs fused with message: bufA(x2) -> bufB(msg) ----
#pragma unroll
    for (int mt = 0; mt < 8; ++mt) {
        const int arow = mt * 16 + c;
        short8v a0 = *(const short8v*)(bufA + swz(arow, 16 * g));
        short8v a1 = *(const short8v*)(bufA + swz(arow, 64 + 16 * g));
        f32x4 t0 = {0.f, 0.f, 0.f, 0.f};
        t0 = __builtin_amdgcn_mfma_f32_16x16x32_bf16(a0, bwf0, t0, 0, 0, 0);
        t0 = __builtin_amdgcn_mfma_f32_16x16x32_bf16(a1, bwf1, t0, 0, 0, 0);
        f32x4 t1 = {0.f, 0.f, 0.f, 0.f};
        t1 = __builtin_amdgcn_mfma_f32_16x16x32_bf16(a0, cwf0, t1, 0, 0, 0);
        t1 = __builtin_amdgcn_mfma_f32_16x16x32_bf16(a1, cwf1, t1, 0, 0, 0);
#pragma unroll
        for (int r = 0; r < 4; ++r) {
            const float gate = 1.f / (1.f + __expf(-(t0[r] + bbB)));
            const float sh = t1[r] + bbC;
            float m = fmaf(gate, vpre[mt * 4 + r], sh);
            m = fmaxf(m, EPS);
            m = m * m;
            *(unsigned short*)(bufB + swz(mt * 16 + 4 * g + r, colbyte)) = bfbits(m);
        }
    }
    __syncthreads();

    // ---- copy-out to CSR slot: 2 threads per edge row, 64B each ----
    {
        const int row = t >> 1;
        const int pos = eposv[row];
        uint4 v[4];
#pragma unroll
        for (int ci = 0; ci < 4; ++ci)
            v[ci] = *(const uint4*)(bufB + swz(row, (t & 1) * 64 + 16 * ci));
        uint4* dp = (uint4*)((unsigned short*)msg + (size_t)pos * DIM + (t & 1) * 32);
#pragma unroll
        for (int ci = 0; ci < 4; ++ci) dp[ci] = v[ci];
    }
}

// ---------------------------------------------------------------------------
// Aggregate: one wave per node; 8 edges per trip via uint4, shfl_xor reduce.
// ---------------------------------------------------------------------------
__global__ __launch_bounds__(256) void aggregate_kernel(
    const __hip_bfloat16* __restrict__ msg,
    const int* __restrict__ offs, const int* __restrict__ cnt,
    float* __restrict__ out)
{
    const int n = (blockIdx.x * 256 + threadIdx.x) >> 6;
    const int lane = threadIdx.x & 63;
    if (n >= N_NODES) return;
    const int start = offs[n];
    const int deg = cnt[n];
    const int rowg = lane >> 3;
    const int dblk = lane & 7;

    const unsigned short* bp = (const unsigned short*)msg + (size_t)start * DIM + dblk * 8;
    float acc0 = 0.f, acc1 = 0.f, acc2 = 0.f, acc3 = 0.f;
    float acc4 = 0.f, acc5 = 0.f, acc6 = 0.f, acc7 = 0.f;
    for (int i = 0; i < deg; i += 8) {
        const int r = i + rowg;
        if (r < deg) {
            const uint4 u = *(const uint4*)(bp + (size_t)r * DIM);
            acc0 += __uint_as_float(u.x << 16);
            acc1 += __uint_as_float(u.x & 0xffff0000u);
            acc2 += __uint_as_float(u.y << 16);
            acc3 += __uint_as_float(u.y & 0xffff0000u);
            acc4 += __uint_as_float(u.z << 16);
            acc5 += __uint_as_float(u.z & 0xffff0000u);
            acc6 += __uint_as_float(u.w << 16);
            acc7 += __uint_as_float(u.w & 0xffff0000u);
        }
    }
#pragma unroll
    for (int m = 8; m <= 32; m <<= 1) {
        acc0 += __shfl_xor(acc0, m, 64);
        acc1 += __shfl_xor(acc1, m, 64);
        acc2 += __shfl_xor(acc2, m, 64);
        acc3 += __shfl_xor(acc3, m, 64);
        acc4 += __shfl_xor(acc4, m, 64);
        acc5 += __shfl_xor(acc5, m, 64);
        acc6 += __shfl_xor(acc6, m, 64);
        acc7 += __shfl_xor(acc7, m, 64);
    }
    if (rowg == 0) {
        const float dinv = (deg > 0) ? 1.0f / (float)deg : 0.0f;
        float4 o0, o1;
        o0.x = sqrtf(acc0 * dinv); o0.y = sqrtf(acc1 * dinv);
        o0.z = sqrtf(acc2 * dinv); o0.w = sqrtf(acc3 * dinv);
        o1.x = sqrtf(acc4 * dinv); o1.y = sqrtf(acc5 * dinv);
        o1.z = sqrtf(acc6 * dinv); o1.w = sqrtf(acc7 * dinv);
        float4* op = (float4*)(out + (size_t)n * DIM + dblk * 8);
        op[0] = o0;
        op[1] = o1;
    }
}

extern "C" void kernel_launch(void* const* d_in, const int* in_sizes, int n_in,
                              void* d_out, int out_size, void* d_ws, size_t ws_size,
                              hipStream_t stream) {
    const float* V   = (const float*)d_in[0];
    const float* E   = (const float*)d_in[1];
    const int*   src = (const int*)d_in[2];
    const int*   dst = (const int*)d_in[3];
    const float* w1  = (const float*)d_in[4];
    const float* b1  = (const float*)d_in[5];
    const float* w2  = (const float*)d_in[6];
    const float* b2  = (const float*)d_in[7];
    const float* Bw  = (const float*)d_in[8];
    const float* Bb  = (const float*)d_in[9];
    const float* Cw  = (const float*)d_in[10];
    const float* Cb  = (const float*)d_in[11];
    const float* pAw = (const float*)d_in[12];
    const float* pAb = (const float*)d_in[13];
    const float* pBw = (const float*)d_in[14];
    const float* pBb = (const float*)d_in[15];

    float* out = (float*)d_out;

    // workspace layout
    char* p = (char*)d_ws;
    float* Vp = (float*)p;                    p += (size_t)N_NODES * DIM * sizeof(float);
    __hip_bfloat16* msg = (__hip_bfloat16*)p; p += (size_t)N_EDGES * DIM * 2;
    int* cnt  = (int*)p; p += (size_t)50176 * 4;
    int* lofs = (int*)p; p += (size_t)50176 * 4;   // becomes final offs after fixup
    int* rank = (int*)p; p += (size_t)N_EDGES * 4;
    unsigned short* wbf = (unsigned short*)p; p += (size_t)6 * 4096 * 2;
    int* btot = (int*)p; p += (size_t)64 * 4;

    prep_kernel<<<6 + SCANA_BLOCKS, 256, 0, stream>>>(w1, w2, Bw, Cw, pAw, pBw, wbf, cnt);
    hist_kernel<<<N_EDGES / 256, 256, 0, stream>>>(dst, cnt, rank);
    node_kernel<<<(N_NODES + 127) / 128, 256, 0, stream>>>(V, wbf, pAb, pBb, Vp);
    scanA_kernel<<<SCANA_BLOCKS, 256, 0, stream>>>(cnt, lofs, btot);
    fixup_kernel<<<SCANA_BLOCKS, 256, 0, stream>>>(btot, lofs);
    edge_kernel<<<N_EDGES / 128, 256, 0, stream>>>(E, src, dst, rank, lofs, wbf,
                                                   b1, b2, Bb, Cb, Vp, msg);
    aggregate_kernel<<<(N_NODES * 64 + 255) / 256, 256, 0, stream>>>(msg, lofs, cnt, out);
}

// Round 14
// 185.366 us; speedup vs baseline: 1.3429x; 1.0569x over previous
//
#include <hip/hip_runtime.h>
#include <hip/hip_bf16.h>
#include <math.h>

// Problem constants (match reference)
#define N_NODES 50000
#define N_EDGES 800000
#define DIM 64
#define NEG_SLOPE 0.2f
#define EPS 1e-5f

typedef __attribute__((ext_vector_type(8))) short short8v;  // 8 bf16 (4 VGPRs)
typedef __attribute__((ext_vector_type(4))) float f32x4;    // MFMA accumulator

__device__ __forceinline__ float lrelu(float v) { return fmaxf(v, NEG_SLOPE * v); }

__device__ __forceinline__ unsigned short bfbits(float v) {
    return __bfloat16_as_ushort(__float2bfloat16(v));
}
// packed pair f32->bf16
__device__ __forceinline__ unsigned pack2bf(float a, float b) {
    union { __hip_bfloat162 h; unsigned u; } cvt;
    cvt.h = __float22bfloat162_rn(make_float2(a, b));
    return cvt.u;
}

// Swizzled byte offset into a 128-byte-stride LDS tile (T2: byte ^= (row&7)<<4).
__device__ __forceinline__ unsigned swz(unsigned row, unsigned byteInRow) {
    return row * 128u + (byteInRow ^ ((row & 7u) << 4));
}

#define LDS_BUF 16384        // node_kernel: 128 rows x 128 bytes
#define EDGE_LDS_BUF 8192    // edge_kernel: 64 rows x 128 bytes

// Fragment-layout weight store: matrix m, entry idx=(ks*4+g)*64+col holds
// short8 {bf16(W[(32ks+8g+j)*64+col]), j=0..7}. One b128 load per fragment.
#define WFRAG_ENTRIES 512   // 2ks * 4g * 64col per matrix

#define SCANA_BLOCKS 49     // 49*1024 = 50176 >= 50000

// ---------------------------------------------------------------------------
// prep: blocks 0..5 convert weight matrices fp32 -> fragment bf16;
//       blocks 6..54 zero cnt (absorbs the memset dispatch)
// ---------------------------------------------------------------------------
__global__ __launch_bounds__(256) void prep_kernel(
    const float* __restrict__ w1, const float* __restrict__ w2,
    const float* __restrict__ Bw, const float* __restrict__ Cw,
    const float* __restrict__ pAw, const float* __restrict__ pBw,
    unsigned short* __restrict__ wbf, int* __restrict__ cnt)
{
    const int t = threadIdx.x;
    if (blockIdx.x >= 6) {
        const int idx = (blockIdx.x - 6) * 1024 + t * 4;
        if (idx + 3 < N_NODES) {
            int4 z = {0, 0, 0, 0};
            *(int4*)(cnt + idx) = z;
        } else {
#pragma unroll
            for (int i = 0; i < 4; ++i)
                if (idx + i < N_NODES) cnt[idx + i] = 0;
        }
        return;
    }
    const float* W;
    switch (blockIdx.x) {
        case 0: W = w1; break;
        case 1: W = w2; break;
        case 2: W = Bw; break;
        case 3: W = Cw; break;
        case 4: W = pAw; break;
        default: W = pBw; break;
    }
#pragma unroll
    for (int ii = 0; ii < 2; ++ii) {
        const int idx = t * 2 + ii;          // 0..511
        const int ks  = idx >> 8;
        const int g   = (idx >> 6) & 3;
        const int col = idx & 63;
        unsigned short* o = wbf + (size_t)blockIdx.x * 4096 + (size_t)idx * 8;
#pragma unroll
        for (int j = 0; j < 8; ++j)
            o[j] = bfbits(W[(32 * ks + 8 * g + j) * DIM + col]);
    }
}

// fragment fetch helper (m = matrix id, ks = k-step)
__device__ __forceinline__ short8v wfrag(const unsigned short* wbf, int m, int ks,
                                         int g, int col) {
    return ((const short8v*)wbf)[m * WFRAG_ENTRIES + (ks * 4 + g) * 64 + col];
}

// ---------------------------------------------------------------------------
// Node pooling via MFMA: Vp = lrelu(lrelu(V)@pAw+pAb)@pBw+pBb
// ---------------------------------------------------------------------------
__global__ __launch_bounds__(256) void node_kernel(
    const float* __restrict__ V,
    const unsigned short* __restrict__ wbf,
    const float* __restrict__ pAb, const float* __restrict__ pBb,
    float* __restrict__ Vp)
{
    __shared__ __align__(16) unsigned char sm[2 * LDS_BUF];
    unsigned char* bufA = sm;
    unsigned char* bufB = sm + LDS_BUF;

    const int t    = threadIdx.x;
    const int w    = t >> 6;
    const int lane = t & 63;
    const int g    = lane >> 4;
    const int c    = lane & 15;
    const int col  = 16 * w + c;
    const unsigned colbyte = (unsigned)col * 2;
    const int base = blockIdx.x * 128;

    {
        const int row = t >> 1;
        const int n = base + row;
        if (n < N_NODES) {
            const float4* Vr = (const float4*)(V + (size_t)n * DIM + (t & 1) * 32);
#pragma unroll
            for (int ci = 0; ci < 4; ++ci) {
                float4 qa = Vr[2 * ci];
                float4 qb = Vr[2 * ci + 1];
                uint4 u;
                u.x = pack2bf(lrelu(qa.x), lrelu(qa.y));
                u.y = pack2bf(lrelu(qa.z), lrelu(qa.w));
                u.z = pack2bf(lrelu(qb.x), lrelu(qb.y));
                u.w = pack2bf(lrelu(qb.z), lrelu(qb.w));
                *(uint4*)(bufA + swz(row, (t & 1) * 64 + 16 * ci)) = u;
            }
        } else {
            uint4 z = {0u, 0u, 0u, 0u};
#pragma unroll
            for (int ci = 0; ci < 4; ++ci)
                *(uint4*)(bufA + swz(row, (t & 1) * 64 + 16 * ci)) = z;
        }
    }

    const short8v af0 = wfrag(wbf, 4, 0, g, col), af1 = wfrag(wbf, 4, 1, g, col);
    const short8v bf0 = wfrag(wbf, 5, 0, g, col), bf1 = wfrag(wbf, 5, 1, g, col);
    const float bbA = pAb[col], bbB = pBb[col];

    __syncthreads();

#pragma unroll
    for (int mt = 0; mt < 8; ++mt) {
        const int arow = mt * 16 + c;
        short8v a0 = *(const short8v*)(bufA + swz(arow, 16 * g));
        short8v a1 = *(const short8v*)(bufA + swz(arow, 64 + 16 * g));
        f32x4 acc = {0.f, 0.f, 0.f, 0.f};
        acc = __builtin_amdgcn_mfma_f32_16x16x32_bf16(a0, af0, acc, 0, 0, 0);
        acc = __builtin_amdgcn_mfma_f32_16x16x32_bf16(a1, af1, acc, 0, 0, 0);
#pragma unroll
        for (int r = 0; r < 4; ++r) {
            const float v = lrelu(acc[r] + bbA);
            *(unsigned short*)(bufB + swz(mt * 16 + 4 * g + r, colbyte)) = bfbits(v);
        }
    }
    __syncthreads();

#pragma unroll
    for (int mt = 0; mt < 8; ++mt) {
        const int arow = mt * 16 + c;
        short8v a0 = *(const short8v*)(bufB + swz(arow, 16 * g));
        short8v a1 = *(const short8v*)(bufB + swz(arow, 64 + 16 * g));
        f32x4 acc = {0.f, 0.f, 0.f, 0.f};
        acc = __builtin_amdgcn_mfma_f32_16x16x32_bf16(a0, bf0, acc, 0, 0, 0);
        acc = __builtin_amdgcn_mfma_f32_16x16x32_bf16(a1, bf1, acc, 0, 0, 0);
#pragma unroll
        for (int r = 0; r < 4; ++r) {
            const int n = base + mt * 16 + 4 * g + r;
            if (n < N_NODES) Vp[(size_t)n * DIM + col] = acc[r] + bbB;
        }
    }
}

// ---------------------------------------------------------------------------
// hist: per-dst count AND per-edge rank (slot within its node)
// ---------------------------------------------------------------------------
__global__ __launch_bounds__(256) void hist_kernel(
    const int* __restrict__ dst, int* __restrict__ cnt, int* __restrict__ rank)
{
    const int e = blockIdx.x * 256 + threadIdx.x;   // 800000 % 256 == 0
    rank[e] = atomicAdd(&cnt[dst[e]], 1);
}

// ---------------------------------------------------------------------------
// scanA: per-1024-node block exclusive scan (lofs) + block total (btot)
// ---------------------------------------------------------------------------
__global__ __launch_bounds__(256) void scanA_kernel(
    const int* __restrict__ cnt, int* __restrict__ lofs, int* __restrict__ btot)
{
    __shared__ int ts[256];
    const int t = threadIdx.x;
    const int nb = blockIdx.x * 1024 + t * 4;
    int4 c = {0, 0, 0, 0};
    if (nb + 3 < N_NODES) {
        c = *(const int4*)(cnt + nb);
    } else {
        if (nb + 0 < N_NODES) c.x = cnt[nb + 0];
        if (nb + 1 < N_NODES) c.y = cnt[nb + 1];
        if (nb + 2 < N_NODES) c.z = cnt[nb + 2];
        if (nb + 3 < N_NODES) c.w = cnt[nb + 3];
    }
    ts[t] = c.x + c.y + c.z + c.w;
    __syncthreads();
    for (int off = 1; off < 256; off <<= 1) {
        const int add = (t >= off) ? ts[t - off] : 0;
        __syncthreads();
        ts[t] += add;
        __syncthreads();
    }
    int4 o;
    o.x = (t == 0) ? 0 : ts[t - 1];
    o.y = o.x + c.x;
    o.z = o.y + c.y;
    o.w = o.z + c.z;
    if (nb + 3 < N_NODES) {
        *(int4*)(lofs + nb) = o;
    } else {
        if (nb + 0 < N_NODES) lofs[nb + 0] = o.x;
        if (nb + 1 < N_NODES) lofs[nb + 1] = o.y;
        if (nb + 2 < N_NODES) lofs[nb + 2] = o.z;
        if (nb + 3 < N_NODES) lofs[nb + 3] = o.w;
    }
    if (t == 255) btot[blockIdx.x] = ts[255];
}

// ---------------------------------------------------------------------------
// fixup: block b adds prefix(btot[0..b)) to its 1024-node slice of lofs,
// making lofs the FINAL global CSR offset array (single-load consumers).
// ---------------------------------------------------------------------------
__global__ __launch_bounds__(256) void fixup_kernel(
    const int* __restrict__ btot, int* __restrict__ lofs)
{
    __shared__ int base_s;
    if (threadIdx.x < 64) {
        int v = (threadIdx.x < blockIdx.x) ? btot[threadIdx.x] : 0;
#pragma unroll
        for (int m = 1; m < 64; m <<= 1) v += __shfl_xor(v, m, 64);
        if (threadIdx.x == 0) base_s = v;
    }
    __syncthreads();
    const int base = base_s;
    const int idx = blockIdx.x * 1024 + threadIdx.x * 4;
    if (idx + 3 < N_NODES) {
        int4 v = *(int4*)(lofs + idx);
        v.x += base; v.y += base; v.z += base; v.w += base;
        *(int4*)(lofs + idx) = v;
    } else {
#pragma unroll
        for (int i = 0; i < 4; ++i)
            if (idx + i < N_NODES) lofs[idx + i] += base;
    }
}

// ---------------------------------------------------------------------------
// MFMA edge pipeline — HALVED TILE for occupancy. Block = 64 edges,
// 256 threads = 4 waves (wave w owns out-dims [16w,16w+16), mt loops 4).
// LDS = 2x8KB + 256B = 16.6KB -> 8 blocks/CU = 32 waves/CU (vs 4 blocks
// at the 128-edge tile). Same phase structure as the 122-131us kernels.
// ---------------------------------------------------------------------------
__global__ __launch_bounds__(256) void edge_kernel(
    const float* __restrict__ E,
    const int* __restrict__ src, const int* __restrict__ dst,
    const int* __restrict__ rank, const int* __restrict__ offs,
    const unsigned short* __restrict__ wbf,
    const float* __restrict__ b1, const float* __restrict__ b2,
    const float* __restrict__ Bb, const float* __restrict__ Cb,
    const float* __restrict__ Vp,
    __hip_bfloat16* __restrict__ msg)
{
    __shared__ __align__(16) unsigned char sm[2 * EDGE_LDS_BUF + 64 * 4];
    unsigned char* bufA = sm;
    unsigned char* bufB = sm + EDGE_LDS_BUF;
    int* eposv = (int*)(sm + 2 * EDGE_LDS_BUF);

    const int t    = threadIdx.x;
    const int w    = t >> 6;
    const int lane = t & 63;
    const int g    = lane >> 4;
    const int c    = lane & 15;
    const int col  = 16 * w + c;
    const unsigned colbyte = (unsigned)col * 2;
    const int base = blockIdx.x * 64;

    // ---- CSR slot via LDS (64 staging threads own the scattered chain) ----
    if (t < 64) {
        eposv[t] = offs[dst[base + t]] + rank[base + t];
    }

    // ---- Vp gather prefetch: 16 independent chains, in flight during GEMMs
    float vpre[16];
#pragma unroll
    for (int mt = 0; mt < 4; ++mt) {
#pragma unroll
        for (int r = 0; r < 4; ++r) {
            const int sv = src[base + mt * 16 + 4 * g + r];
            vpre[mt * 4 + r] = Vp[(size_t)sv * DIM + col];
        }
    }

    // ---- stage E tile (fp32 -> bf16, swizzled): 4 threads/row, 32B each ----
    {
        const int row = t >> 2;
        const int q   = t & 3;
        const float4* Ep = (const float4*)(E + (size_t)(base + row) * DIM + q * 16);
        float4 qa = Ep[0], qb = Ep[1], qc = Ep[2], qd = Ep[3];
        uint4 u0, u1;
        u0.x = pack2bf(qa.x, qa.y); u0.y = pack2bf(qa.z, qa.w);
        u0.z = pack2bf(qb.x, qb.y); u0.w = pack2bf(qb.z, qb.w);
        u1.x = pack2bf(qc.x, qc.y); u1.y = pack2bf(qc.z, qc.w);
        u1.z = pack2bf(qd.x, qd.y); u1.w = pack2bf(qd.z, qd.w);
        *(uint4*)(bufA + swz(row, q * 32))      = u0;
        *(uint4*)(bufA + swz(row, q * 32 + 16)) = u1;
    }

    // ---- weight fragments: one b128 load each ----
    const short8v w1f0 = wfrag(wbf, 0, 0, g, col), w1f1 = wfrag(wbf, 0, 1, g, col);
    const short8v w2f0 = wfrag(wbf, 1, 0, g, col), w2f1 = wfrag(wbf, 1, 1, g, col);
    const short8v bwf0 = wfrag(wbf, 2, 0, g, col), bwf1 = wfrag(wbf, 2, 1, g, col);
    const short8v cwf0 = wfrag(wbf, 3, 0, g, col), cwf1 = wfrag(wbf, 3, 1, g, col);
    const float bb1 = b1[col], bb2 = b2[col], bbB = Bb[col], bbC = Cb[col];

    __syncthreads();

    // ---- layer 1: x1 = relu(E @ w1 + b1) : bufA -> bufB ----
#pragma unroll
    for (int mt = 0; mt < 4; ++mt) {
        const int arow = mt * 16 + c;
        short8v a0 = *(const short8v*)(bufA + swz(arow, 16 * g));
        short8v a1 = *(const short8v*)(bufA + swz(arow, 64 + 16 * g));
        f32x4 acc = {0.f, 0.f, 0.f, 0.f};
        acc = __builtin_amdgcn_mfma_f32_16x16x32_bf16(a0, w1f0, acc, 0, 0, 0);
        acc = __builtin_amdgcn_mfma_f32_16x16x32_bf16(a1, w1f1, acc, 0, 0, 0);
#pragma unroll
        for (int r = 0; r < 4; ++r) {
            const float v = fmaxf(acc[r] + bb1, 0.f);
            *(unsigned short*)(bufB + swz(mt * 16 + 4 * g + r, colbyte)) = bfbits(v);
        }
    }
    __syncthreads();

    // ---- layer 2: x2 = relu(x1 @ w2 + b2) : bufB -> bufA ----
#pragma unroll
    for (int mt = 0; mt < 4; ++mt) {
        const int arow = mt * 16 + c;
        short8v a0 = *(const short8v*)(bufB + swz(arow, 16 * g));
        short8v a1 = *(const short8v*)(bufB + swz(arow, 64 + 16 * g));
        f32x4 acc = {0.f, 0.f, 0.f, 0.f};
        acc = __builtin_amdgcn_mfma_f32_16x16x32_bf16(a0, w2f0, acc, 0, 0, 0);
        acc = __builtin_amdgcn_mfma_f32_16x16x32_bf16(a1, w2f1, acc, 0, 0, 0);
#pragma unroll
        for (int r = 0; r < 4; ++r) {
            const float v = fmaxf(acc[r] + bb2, 0.f);
            *(unsigned short*)(bufA + swz(mt * 16 + 4 * g + r, colbyte)) = bfbits(v);
        }
    }
    __syncthreads();

    // ---- gate + shift GEMMs fused with message: bufA(x2) -> bufB(msg) ----
#pragma unroll
    for (int mt = 0; mt < 4; ++mt) {
        const int arow = mt * 16 + c;
        short8v a0 = *(const short8v*)(bufA + swz(arow, 16 * g));
        short8v a1 = *(const short8v*)(bufA + swz(arow, 64 + 16 * g));
        f32x4 t0 = {0.f, 0.f, 0.f, 0.f};
        t0 = __builtin_amdgcn_mfma_f32_16x16x32_bf16(a0, bwf0, t0, 0, 0, 0);
        t0 = __builtin_amdgcn_mfma_f32_16x16x32_bf16(a1, bwf1, t0, 0, 0, 0);
        f32x4 t1 = {0.f, 0.f, 0.f, 0.f};
        t1 = __builtin_amdgcn_mfma_f32_16x16x32_bf16(a0, cwf0, t1, 0, 0, 0);
        t1 = __builtin_amdgcn_mfma_f32_16x16x32_bf16(a1, cwf1, t1, 0, 0, 0);
#pragma unroll
        for (int r = 0; r < 4; ++r) {
            const float gate = 1.f / (1.f + __expf(-(t0[r] + bbB)));
            const float sh = t1[r] + bbC;
            float m = fmaf(gate, vpre[mt * 4 + r], sh);
            m = fmaxf(m, EPS);
            m = m * m;
            *(unsigned short*)(bufB + swz(mt * 16 + 4 * g + r, colbyte)) = bfbits(m);
        }
    }
    __syncthreads();

    // ---- copy-out to CSR slot: 4 threads per edge row, 32B each ----
    {
        const int row = t >> 2;
        const int q   = t & 3;
        const int pos = eposv[row];
        uint4 v0 = *(const uint4*)(bufB + swz(row, q * 32));
        uint4 v1 = *(const uint4*)(bufB + swz(row, q * 32 + 16));
        uint4* dp = (uint4*)((unsigned short*)msg + (size_t)pos * DIM + q * 16);
        dp[0] = v0;
        dp[1] = v1;
    }
}

// ---------------------------------------------------------------------------
// Aggregate: one wave per node; 8 edges per trip via uint4, shfl_xor reduce.
// ---------------------------------------------------------------------------
__global__ __launch_bounds__(256) void aggregate_kernel(
    const __hip_bfloat16* __restrict__ msg,
    const int* __restrict__ offs, const int* __restrict__ cnt,
    float* __restrict__ out)
{
    const int n = (blockIdx.x * 256 + threadIdx.x) >> 6;
    const int lane = threadIdx.x & 63;
    if (n >= N_NODES) return;
    const int start = offs[n];
    const int deg = cnt[n];
    const int rowg = lane >> 3;
    const int dblk = lane & 7;

    const unsigned short* bp = (const unsigned short*)msg + (size_t)start * DIM + dblk * 8;
    float acc0 = 0.f, acc1 = 0.f, acc2 = 0.f, acc3 = 0.f;
    float acc4 = 0.f, acc5 = 0.f, acc6 = 0.f, acc7 = 0.f;
    for (int i = 0; i < deg; i += 8) {
        const int r = i + rowg;
        if (r < deg) {
            const uint4 u = *(const uint4*)(bp + (size_t)r * DIM);
            acc0 += __uint_as_float(u.x << 16);
            acc1 += __uint_as_float(u.x & 0xffff0000u);
            acc2 += __uint_as_float(u.y << 16);
            acc3 += __uint_as_float(u.y & 0xffff0000u);
            acc4 += __uint_as_float(u.z << 16);
            acc5 += __uint_as_float(u.z & 0xffff0000u);
            acc6 += __uint_as_float(u.w << 16);
            acc7 += __uint_as_float(u.w & 0xffff0000u);
        }
    }
#pragma unroll
    for (int m = 8; m <= 32; m <<= 1) {
        acc0 += __shfl_xor(acc0, m, 64);
        acc1 += __shfl_xor(acc1, m, 64);
        acc2 += __shfl_xor(acc2, m, 64);
        acc3 += __shfl_xor(acc3, m, 64);
        acc4 += __shfl_xor(acc4, m, 64);
        acc5 += __shfl_xor(acc5, m, 64);
        acc6 += __shfl_xor(acc6, m, 64);
        acc7 += __shfl_xor(acc7, m, 64);
    }
    if (rowg == 0) {
        const float dinv = (deg > 0) ? 1.0f / (float)deg : 0.0f;
        float4 o0, o1;
        o0.x = sqrtf(acc0 * dinv); o0.y = sqrtf(acc1 * dinv);
        o0.z = sqrtf(acc2 * dinv); o0.w = sqrtf(acc3 * dinv);
        o1.x = sqrtf(acc4 * dinv); o1.y = sqrtf(acc5 * dinv);
        o1.z = sqrtf(acc6 * dinv); o1.w = sqrtf(acc7 * dinv);
        float4* op = (float4*)(out + (size_t)n * DIM + dblk * 8);
        op[0] = o0;
        op[1] = o1;
    }
}

extern "C" void kernel_launch(void* const* d_in, const int* in_sizes, int n_in,
                              void* d_out, int out_size, void* d_ws, size_t ws_size,
                              hipStream_t stream) {
    const float* V   = (const float*)d_in[0];
    const float* E   = (const float*)d_in[1];
    const int*   src = (const int*)d_in[2];
    const int*   dst = (const int*)d_in[3];
    const float* w1  = (const float*)d_in[4];
    const float* b1  = (const float*)d_in[5];
    const float* w2  = (const float*)d_in[6];
    const float* b2  = (const float*)d_in[7];
    const float* Bw  = (const float*)d_in[8];
    const float* Bb  = (const float*)d_in[9];
    const float* Cw  = (const float*)d_in[10];
    const float* Cb  = (const float*)d_in[11];
    const float* pAw = (const float*)d_in[12];
    const float* pAb = (const float*)d_in[13];
    const float* pBw = (const float*)d_in[14];
    const float* pBb = (const float*)d_in[15];

    float* out = (float*)d_out;

    // workspace layout
    char* p = (char*)d_ws;
    float* Vp = (float*)p;                    p += (size_t)N_NODES * DIM * sizeof(float);
    __hip_bfloat16* msg = (__hip_bfloat16*)p; p += (size_t)N_EDGES * DIM * 2;
    int* cnt  = (int*)p; p += (size_t)50176 * 4;
    int* lofs = (int*)p; p += (size_t)50176 * 4;   // becomes final offs after fixup
    int* rank = (int*)p; p += (size_t)N_EDGES * 4;
    unsigned short* wbf = (unsigned short*)p; p += (size_t)6 * 4096 * 2;
    int* btot = (int*)p; p += (size_t)64 * 4;

    prep_kernel<<<6 + SCANA_BLOCKS, 256, 0, stream>>>(w1, w2, Bw, Cw, pAw, pBw, wbf, cnt);
    hist_kernel<<<N_EDGES / 256, 256, 0, stream>>>(dst, cnt, rank);
    node_kernel<<<(N_NODES + 127) / 128, 256, 0, stream>>>(V, wbf, pAb, pBb, Vp);
    scanA_kernel<<<SCANA_BLOCKS, 256, 0, stream>>>(cnt, lofs, btot);
    fixup_kernel<<<SCANA_BLOCKS, 256, 0, stream>>>(btot, lofs);
    edge_kernel<<<N_EDGES / 64, 256, 0, stream>>>(E, src, dst, rank, lofs, wbf,
                                                  b1, b2, Bb, Cb, Vp, msg);
    aggregate_kernel<<<(N_NODES * 64 + 255) / 256, 256, 0, stream>>>(msg, lofs, cnt, out);
}